// Round 1
// 766.808 us; speedup vs baseline: 1.0173x; 1.0173x over previous
//
#include <hip/hip_runtime.h>

// ---------------------------------------------------------------------------
// Fused "adjacency attention":
//   out = beta*softmax(q k^T/8 + adj) @ v, diagonal of score matrix replaced
//   by alpha before PV.
// Round 3: operand-swapped QK^T (mfma(K,Q)) makes the q-row lane-resident:
//   - softmax row-reduce: 32 ds_swizzle/iter -> 4 (xor16/xor32 only)
//   - adj bias: direct global dwordx4 in C-layout (64B-line coalesced),
//     adjBuf LDS staging deleted entirely
//   - P->PV round trip: 4x ds_write_b64 + 2x ds_read_b128 (was 16 u16 + 2)
//   - per-row softmax state (m, l, diag) is scalar per lane
// DS-pipe wave-ops/iter: ~92 -> ~36. K/V staging + barriers unchanged.
// ---------------------------------------------------------------------------

#define LOG2E 1.4426950408889634f

typedef __attribute__((ext_vector_type(8))) short  short8;   // 8 x bf16 frag
typedef __attribute__((ext_vector_type(4))) short  short4v;
typedef __attribute__((ext_vector_type(4))) float  float4v;

constexpr int NH    = 8;
constexpr int N     = 4096;
constexpr int D     = 64;
constexpr int BM    = 64;          // q rows per workgroup
constexpr int BN    = 64;          // kv per tile
constexpr int TILES = N / BN;      // 64
constexpr int LDK   = 80;          // padded LDS row stride (bf16 units), 160 B
constexpr int LDP   = 72;          // P LDS row stride (bf16 units), 144 B

__device__ __forceinline__ short f2bf(float f) {
    unsigned u = __builtin_bit_cast(unsigned, f);
    u = (u + 0x7fffu + ((u >> 16) & 1u)) >> 16;   // RNE truncate to bf16
    return (short)u;
}

__global__ __launch_bounds__(256, 2)
void attn_adj_kernel(const float* __restrict__ gq, const float* __restrict__ gk,
                     const float* __restrict__ gv, const float* __restrict__ gadj,
                     const float* __restrict__ galpha, const float* __restrict__ gbeta,
                     float* __restrict__ gout)
{
    __shared__ short qLds[BM * LDK];        // 10,240 B (preloop only)
    __shared__ short kBuf[2][BN * LDK];     // 20,480 B
    __shared__ short vtBuf[2][D * LDK];     // 20,480 B  [d][kv]
    __shared__ short pLds[BM * LDP];        //  9,216 B  rows wave-private

    const int tid  = threadIdx.x;
    const int lane = tid & 63;
    const int wv   = tid >> 6;      // wave 0..3 -> q rows [16*wv, 16*wv+16)
    const int l15  = lane & 15;
    const int l4   = lane >> 4;     // 0..3

    // XCD swizzle: head = bx & 7 so each XCD's resident WGs share one head's K/V.
    const int h  = blockIdx.x & 7;
    const int qt = blockIdx.x >> 3;      // 0..63
    const int q0 = qt * BM;

    // ---- staging maps (256 threads)
    const int srow   = tid >> 2;         // 0..63  (K / Q row)
    const int schunk = tid & 3;          // 16-float chunk
    const int vd     = (tid & 15) * 4;   // V: d base
    const int vkv    = (tid >> 4) * 4;   // V: kv base

    const float* qp = gq + ((size_t)h * N + q0 + srow) * D + schunk * 16;
    const float* kp = gk + ((size_t)h * N + srow) * D + schunk * 16;
    const float* vp = gv + ((size_t)h * N + vkv) * D + vd;

    const int rowl = 16 * wv + l4 * 4;   // Oacc row base (epilogue)

    // ---- adj direct C-layout stream: swapped QK puts this lane's q row at
    // l15, so the 4 floats it needs per ct-block are CONTIGUOUS in gadj.
    // Per instruction: 4 lanes (l4 groups... actually the 4 l4 variants) x 16B
    // cover a full 64B line; 16 rows per wave instruction, all lines 100% used.
    const float* aRow = gadj + ((size_t)h * N + q0 + 16 * wv + l15) * N + l4 * 4;

    float4v kr[4], vr[4], qr[4];
    #pragma unroll
    for (int s = 0; s < 4; ++s) qr[s] = ((const float4v*)qp)[s];
    #pragma unroll
    for (int s = 0; s < 4; ++s) kr[s] = ((const float4v*)kp)[s];
    #pragma unroll
    for (int r = 0; r < 4; ++r) vr[r] = *(const float4v*)(vp + r * D);

    // stage K/V tile into LDS buffer `buf` from kr/vr registers
    auto stageKV = [&](int buf) {
        short8 a, b;
        #pragma unroll
        for (int i = 0; i < 8; ++i) a[i] = f2bf(kr[i >> 2][i & 3]);
        #pragma unroll
        for (int i = 0; i < 8; ++i) b[i] = f2bf(kr[2 + (i >> 2)][i & 3]);
        short* kd = &kBuf[buf][srow * LDK + schunk * 16];
        *(short8*)kd = a;
        *(short8*)(kd + 8) = b;
        #pragma unroll
        for (int i = 0; i < 4; ++i) {       // 4x4 register transpose of V
            short4v t;
            t[0] = f2bf(vr[0][i]); t[1] = f2bf(vr[1][i]);
            t[2] = f2bf(vr[2][i]); t[3] = f2bf(vr[3][i]);
            *(short4v*)&vtBuf[buf][(vd + i) * LDK + vkv] = t;
        }
    };

    // Q (pre-scaled into base-2 softmax domain) + K/V tile 0
    {
        constexpr float QSCALE = 0.125f * LOG2E;   // 1/sqrt(64) * log2(e)
        short8 a, b;
        #pragma unroll
        for (int i = 0; i < 8; ++i) a[i] = f2bf(qr[i >> 2][i & 3] * QSCALE);
        #pragma unroll
        for (int i = 0; i < 8; ++i) b[i] = f2bf(qr[2 + (i >> 2)][i & 3] * QSCALE);
        short* qd = &qLds[srow * LDK + schunk * 16];
        *(short8*)qd = a;
        *(short8*)(qd + 8) = b;
    }
    stageKV(0);
    __syncthreads();

    // Q B-fragments live in registers for the whole kernel
    short8 qf[2];
    #pragma unroll
    for (int kf = 0; kf < 2; ++kf)
        qf[kf] = *(const short8*)&qLds[(16 * wv + l15) * LDK + kf * 32 + l4 * 8];

    // adj prefetch, depth 2 (two register buffers)
    float4v adjA[4], adjB[4];
    #pragma unroll
    for (int ct = 0; ct < 4; ++ct)
        adjA[ct] = __builtin_nontemporal_load((const float4v*)(aRow + ct * 16));
    #pragma unroll
    for (int ct = 0; ct < 4; ++ct)
        adjB[ct] = __builtin_nontemporal_load((const float4v*)(aRow + 64 + ct * 16));

    float4v Oacc[4];
    #pragma unroll
    for (int ct = 0; ct < 4; ++ct) Oacc[ct] = (float4v)(0.0f);
    float mrun  = -3.0e38f;
    float lrun  = 0.0f;
    float sdiag = -3.0e38f;

    auto body = [&](int j, float4v (&cur)[4]) {
        const int  c    = j & 1;
        const bool last = (j + 1 == TILES);

        // issue next tile's K/V global loads early
        if (!last) { kp += BN * D; vp += BN * D; }
        #pragma unroll
        for (int s = 0; s < 4; ++s) kr[s] = ((const float4v*)kp)[s];
        #pragma unroll
        for (int r = 0; r < 4; ++r) vr[r] = *(const float4v*)(vp + r * D);

        // ---- S^T = K * Qs^T (swapped operands; base-2 domain via Q pre-scale)
        // s2[ct][r] = S[q = 16wv + l15][kv = 16ct + 4*l4 + r]
        float4v s2[4];
        #pragma unroll
        for (int ct = 0; ct < 4; ++ct) {
            float4v acc = (float4v)(0.0f);
            #pragma unroll
            for (int kf = 0; kf < 2; ++kf) {
                short8 af = *(const short8*)&kBuf[c][(ct * 16 + l15) * LDK + kf * 32 + l4 * 8];
                acc = __builtin_amdgcn_mfma_f32_16x16x32_bf16(af, qf[kf], acc, 0, 0, 0);
            }
            s2[ct] = acc;
        }

        // add adjacency bias (times log2e) straight from registers
        #pragma unroll
        for (int ct = 0; ct < 4; ++ct)
            #pragma unroll
            for (int r = 0; r < 4; ++r)
                s2[ct][r] = __builtin_fmaf(cur[ct][r], LOG2E, s2[ct][r]);

        // issue adj loads for tile j+2 into the same register buffer
        {
            const int    tl  = (j + 2 < TILES) ? (j + 2) : (TILES - 1);
            const float* ap2 = aRow + (size_t)tl * 64;
            #pragma unroll
            for (int ct = 0; ct < 4; ++ct)
                cur[ct] = __builtin_nontemporal_load((const float4v*)(ap2 + ct * 16));
        }

        // ---- diagonal capture (tile j == qt holds all diagonals of this WG)
        // lane's diag (kv = 16wv + l15) lives in s2[wv][l15&3] of lane
        // (l4 = l15>>2, same l15); fetch with 4 shuffles + select.
        if (j == qt) {
            #pragma unroll
            for (int r = 0; r < 4; ++r) {
                float dv = (wv == 0) ? s2[0][r] : (wv == 1) ? s2[1][r]
                         : (wv == 2) ? s2[2][r] : s2[3][r];
                float tmp = __shfl(dv, ((l15 >> 2) << 4) | l15);
                if ((l15 & 3) == r) sdiag = tmp;
            }
        }

        // ---- online softmax: row is lane-resident -> in-register tree + 2 shuffles
        float cmax0 = fmaxf(fmaxf(s2[0][0], s2[0][1]), fmaxf(s2[0][2], s2[0][3]));
        float cmax1 = fmaxf(fmaxf(s2[1][0], s2[1][1]), fmaxf(s2[1][2], s2[1][3]));
        float cmax2 = fmaxf(fmaxf(s2[2][0], s2[2][1]), fmaxf(s2[2][2], s2[2][3]));
        float cmax3 = fmaxf(fmaxf(s2[3][0], s2[3][1]), fmaxf(s2[3][2], s2[3][3]));
        float t = fmaxf(fmaxf(cmax0, cmax1), fmaxf(cmax2, cmax3));
        t = fmaxf(t, __shfl_xor(t, 16));
        t = fmaxf(t, __shfl_xor(t, 32));
        float mn = fmaxf(mrun, t);
        float al = __builtin_amdgcn_exp2f(mrun - mn);
        mrun = mn;

        float p[4][4];
        #pragma unroll
        for (int ct = 0; ct < 4; ++ct)
            #pragma unroll
            for (int r = 0; r < 4; ++r)
                p[ct][r] = __builtin_amdgcn_exp2f(s2[ct][r] - mn);

        float ps = ((p[0][0] + p[0][1]) + (p[0][2] + p[0][3]))
                 + ((p[1][0] + p[1][1]) + (p[1][2] + p[1][3]))
                 + ((p[2][0] + p[2][1]) + (p[2][2] + p[2][3]))
                 + ((p[3][0] + p[3][1]) + (p[3][2] + p[3][3]));
        ps += __shfl_xor(ps, 16);
        ps += __shfl_xor(ps, 32);
        lrun = __builtin_fmaf(lrun, al, ps);

        // rescale O: Oacc rows are 4*l4+r -> fetch that row's al (4 bpermutes)
        float alR[4];
        #pragma unroll
        for (int r = 0; r < 4; ++r)
            alR[r] = __shfl(al, (l4 << 4) | (4 * l4 + r));
        #pragma unroll
        for (int ct = 0; ct < 4; ++ct)
            #pragma unroll
            for (int r = 0; r < 4; ++r)
                Oacc[ct][r] *= alR[r];

        // ---- P -> LDS (contiguous b64 per ct; rows wave-private, no barrier)
        #pragma unroll
        for (int ct = 0; ct < 4; ++ct) {
            short4v t4;
            t4[0] = f2bf(p[ct][0]); t4[1] = f2bf(p[ct][1]);
            t4[2] = f2bf(p[ct][2]); t4[3] = f2bf(p[ct][3]);
            *(short4v*)&pLds[(16 * wv + l15) * LDP + ct * 16 + l4 * 4] = t4;
        }

        // ---- O += P @ V
        short8 pf0 = *(const short8*)&pLds[(16 * wv + l15) * LDP + l4 * 8];
        short8 pf1 = *(const short8*)&pLds[(16 * wv + l15) * LDP + 32 + l4 * 8];
        #pragma unroll
        for (int ct = 0; ct < 4; ++ct) {
            short8 b0 = *(const short8*)&vtBuf[c][(ct * 16 + l15) * LDK + l4 * 8];
            short8 b1 = *(const short8*)&vtBuf[c][(ct * 16 + l15) * LDK + 32 + l4 * 8];
            Oacc[ct] = __builtin_amdgcn_mfma_f32_16x16x32_bf16(pf0, b0, Oacc[ct], 0, 0, 0);
            Oacc[ct] = __builtin_amdgcn_mfma_f32_16x16x32_bf16(pf1, b1, Oacc[ct], 0, 0, 0);
        }

        // stage next K/V tile into the other buffer; one barrier per iteration
        stageKV(c ^ 1);
        __syncthreads();
    };

    for (int jj = 0; jj < TILES; jj += 2) {
        body(jj,     adjA);
        body(jj + 1, adjB);
    }

    // ---- epilogue: out = beta*O/l + (alpha - beta*p_diag)*v[row]
    // per-lane scalars are for row l15; shuffle to Oacc's rows 4*l4+r.
    const float s_alpha = galpha[h];
    const float s_beta  = gbeta[h];
    float inv = 1.0f / lrun;
    float pd  = __builtin_amdgcn_exp2f(sdiag - mrun) * inv;
    float cO  = s_beta * inv;
    float cV  = s_alpha - s_beta * pd;

    const float* vrow = gv  + ((size_t)h * N + q0 + rowl) * D + l15;
    float*       op   = gout + ((size_t)h * N + q0 + rowl) * D + l15;
    #pragma unroll
    for (int r = 0; r < 4; ++r) {
        float cOr = __shfl(cO, (l4 << 4) | (4 * l4 + r));
        float cVr = __shfl(cV, (l4 << 4) | (4 * l4 + r));
        #pragma unroll
        for (int ct = 0; ct < 4; ++ct) {
            float vvv = vrow[(size_t)r * D + ct * 16];
            op[(size_t)r * D + ct * 16] = cOr * Oacc[ct][r] + cVr * vvv;
        }
    }
}

extern "C" void kernel_launch(void* const* d_in, const int* in_sizes, int n_in,
                              void* d_out, int out_size, void* d_ws, size_t ws_size,
                              hipStream_t stream) {
    const float* q     = (const float*)d_in[0];
    const float* k     = (const float*)d_in[1];
    const float* v     = (const float*)d_in[2];
    const float* adj   = (const float*)d_in[3];
    const float* alpha = (const float*)d_in[4];
    const float* beta  = (const float*)d_in[5];
    float* out = (float*)d_out;

    dim3 grid(NH * (N / BM));   // 512 WGs = 2 per CU
    dim3 block(256);
    attn_adj_kernel<<<grid, block, 0, stream>>>(q, k, v, adj, alpha, beta, out);
}